// Round 3
// baseline (194.270 us; speedup 1.0000x reference)
//
#include <hip/hip_runtime.h>
#include <math.h>

#define N_S 32
#define C_DIM 3
#define F_DIM 3277
#define T_DIM 256
#define FT (F_DIM * T_DIM)        /* 838912  */
#define CFT (C_DIM * FT)          /* 2516736 */
#define FC_IDX 1084
#define NOISE_LO_END 1638         /* noise rows: [0,1638) and [1966,3277) */
#define SKIP 328
#define N_NOISE 2949
#define PLANE4 (FT / 4)           /* 209728 float4 per (n,c) plane */
#define NQ4 (N_NOISE * 64)        /* 188736 noise float4s per plane */
#define S_CHUNK 16
#define NPART (C_DIM * S_CHUNK)   /* 48 partials per sample */
#define Q_PER (NQ4 / S_CHUNK)     /* 11796 exactly (16*11796 == 188736) */
#define TOTAL4 ((N_S * CFT) / 4)  /* 20,133,888 */
#define FILL_BLOCKS 2048

struct WS {
  float              noise_partial[N_S][NPART];
  int                mid[N_S];
  int                hb[N_S];
  unsigned long long tbits[N_S][4];
};

// ---------------- K0: pure zero-fill of d_out (proven-peak pattern) ----------
__global__ __launch_bounds__(256) void k_fill(float4* __restrict__ ov) {
  const float4 z = {0.f, 0.f, 0.f, 0.f};
  for (int i = blockIdx.x * 256 + (int)threadIdx.x; i < TOTAL4;
       i += FILL_BLOCKS * 256) {
    ov[i] = z;
  }
}

// ---------------- K1: noise partial sums — pure contiguous read --------------
__global__ __launch_bounds__(256) void k_noise(const float4* __restrict__ xv,
                                               WS* __restrict__ ws) {
  int b   = blockIdx.x;
  int n   = b / NPART;
  int rem = b - n * NPART;        // c = rem>>4, s = rem&15
  int c   = rem >> 4;
  int s   = rem & 15;
  const float4* plane = xv + (size_t)n * (CFT / 4) + (size_t)c * PLANE4;
  int lo = s * Q_PER;
  int hi = lo + Q_PER;
  float acc = 0.f;
  #pragma unroll 4
  for (int q = lo + (int)threadIdx.x; q < hi; q += 256) {
    // noise-float4-index -> plane float4 address (skip in-band rows 1638..1965)
    int a = q + ((q >= NOISE_LO_END * 64) ? SKIP * 64 : 0);
    float4 v = plane[a];
    acc += fabsf(v.x) + fabsf(v.y) + fabsf(v.z) + fabsf(v.w);
  }
  for (int off = 32; off; off >>= 1) acc += __shfl_down(acc, off);
  __shared__ double wsum[4];
  int w = threadIdx.x >> 6, lane = threadIdx.x & 63;
  if (lane == 0) wsum[w] = (double)acc;
  __syncthreads();
  if (threadIdx.x == 0) {
    ws->noise_partial[n][rem] = (float)(wsum[0] + wsum[1] + wsum[2] + wsum[3]);
  }
}

// ------- K2: per-sample stats (argmax, sig, snr, hb) — numerics unchanged ----
__global__ __launch_bounds__(256) void k_stats(const float* __restrict__ x,
                                               WS* __restrict__ ws) {
  int n = blockIdx.x;
  int t = threadIdx.x;
  const float* p = x + (size_t)n * CFT + (size_t)FC_IDX * T_DIM + t;
  float m = fabsf(p[0]) + fabsf(p[FT]) + fabsf(p[2 * FT]);

  __shared__ float  smag[256];
  __shared__ float  sv[256];
  __shared__ int    si[256];
  __shared__ double sd[256];
  smag[t] = m; sv[t] = m; si[t] = t;
  sd[t] = (t < NPART) ? (double)ws->noise_partial[n][t] : 0.0;
  __syncthreads();
  for (int s = 128; s > 0; s >>= 1) {
    if (t < s) {
      if (sv[t + s] > sv[t] || (sv[t + s] == sv[t] && si[t + s] < si[t])) {
        sv[t] = sv[t + s]; si[t] = si[t + s];
      }
      sd[t] += sd[t + s];
    }
    __syncthreads();
  }
  if (t == 0) {
    int mid = si[0];
    double noise_d = sd[0] / ((double)N_NOISE * (double)T_DIM);
    int lo = mid - 8; if (lo < 0) lo = 0;
    int hi = mid + 8; if (hi > T_DIM) hi = T_DIM;
    double sig_d = 0.0;
    for (int tt = lo; tt < hi; ++tt) sig_d += (double)smag[tt];
    float sig = (float)sig_d, noise = (float)noise_d;
    float d   = sig - noise;
    float snr = 10.0f * log10f((d * d) / (noise * noise));
    float hbf = 12.5f * (snr - 20.0f) + 27.0f;
    int hb = (int)truncf(hbf);
    if (hb < 8) hb = 8;
    ws->mid[n] = mid;
    ws->hb[n]  = hb;
    int wlo = mid - 8, whi = mid + 8;
    #pragma unroll
    for (int wd = 0; wd < 4; ++wd) {
      int base = wd * 64;
      int a = wlo - base; if (a < 0) a = 0;
      int b = whi - base; if (b > 64) b = 64;
      unsigned long long msk = 0ULL;
      if (b > a) {
        unsigned long long hiM = (b >= 64) ? ~0ULL : ((1ULL << b) - 1ULL);
        unsigned long long loM = (1ULL << a) - 1ULL;
        msk = hiM & ~loM;
      }
      ws->tbits[n][wd] = msk;
    }
  }
}

// ---- K3: one block per freq row; rewrite rows inside the union band ---------
__global__ __launch_bounds__(256) void k_band(const float* __restrict__ x,
                                              float* __restrict__ out,
                                              const WS* __restrict__ ws) {
  __shared__ unsigned long long um[4];
  int f = blockIdx.x;
  int t = threadIdx.x;
  if (t < 4) {
    unsigned long long m = 0ULL;
    #pragma unroll 4
    for (int n = 0; n < N_S; ++n) {
      int hb = ws->hb[n];
      if (f >= FC_IDX - hb && f < FC_IDX + hb) m |= ws->tbits[n][t];
    }
    um[t] = m;
  }
  __syncthreads();
  if ((um[0] | um[1] | um[2] | um[3]) == 0ULL) return;  // row outside all bands

  bool keep = (um[t >> 6] >> (t & 63)) & 1ULL;
  const float* xr   = x   + (size_t)f * T_DIM + t;
  float*       orow = out + (size_t)f * T_DIM + t;
  #pragma unroll 4
  for (int nc = 0; nc < N_S * C_DIM; ++nc) {
    size_t off = (size_t)nc * FT;
    float v = keep ? xr[off] : 0.f;
    orow[off] = v;
  }
}

extern "C" void kernel_launch(void* const* d_in, const int* in_sizes, int n_in,
                              void* d_out, int out_size, void* d_ws, size_t ws_size,
                              hipStream_t stream) {
  const float* x   = (const float*)d_in[0];
  float*       out = (float*)d_out;
  WS*          ws  = (WS*)d_ws;

  k_fill <<<FILL_BLOCKS, 256, 0, stream>>>((float4*)out);
  k_noise<<<N_S * NPART, 256, 0, stream>>>((const float4*)x, ws);
  k_stats<<<N_S, 256, 0, stream>>>(x, ws);
  k_band <<<F_DIM, 256, 0, stream>>>(x, out, ws);
}

// Round 4
// 166.663 us; speedup vs baseline: 1.1656x; 1.1656x over previous
//
#include <hip/hip_runtime.h>
#include <math.h>

#define N_S 32
#define C_DIM 3
#define F_DIM 3277
#define T_DIM 256
#define FT (F_DIM * T_DIM)        /* 838912  */
#define CFT (C_DIM * FT)          /* 2516736 */
#define FC_IDX 1084
#define NOISE_LO_END 1638         /* noise rows: [0,1638) and [1966,3277) */
#define SKIP 328
#define N_NOISE 2949
#define RPC 12                    /* noise rows per chunk (3 per wave) */
#define NCHUNK ((N_NOISE + RPC - 1) / RPC)  /* 246 */
#define PLANES (N_S * C_DIM)      /* 96 */
#define P4 (FT / 4)               /* 209728 float4 per plane */

struct WS {
  float              noise_partial[N_S][256];
  int                mid[N_S];
  int                hb[N_S];
  unsigned long long tbits[N_S][4];
};

// ---- K1: noise partial sums — VERBATIM from round-1 (best round) ------------
__global__ __launch_bounds__(256) void k_noise(const float* __restrict__ x, WS* __restrict__ ws) {
  int blk   = blockIdx.x;
  int n     = blk / NCHUNK;
  int chunk = blk - n * NCHUNK;
  int w     = threadIdx.x >> 6;   // wave id 0..3
  int lane  = threadIdx.x & 63;
  float s = 0.f;
  const float* base_n = x + (size_t)n * CFT + lane * 4;
  #pragma unroll
  for (int i = 0; i < RPC / 4; ++i) {
    int j = chunk * RPC + w + i * 4;              // noise-row index
    if (j < N_NOISE) {
      int k = (j < NOISE_LO_END) ? j : j + SKIP;  // actual freq row
      const float* p = base_n + (size_t)k * T_DIM;
      #pragma unroll
      for (int c = 0; c < C_DIM; ++c) {
        float4 v = *reinterpret_cast<const float4*>(p + (size_t)c * FT);
        s += fabsf(v.x) + fabsf(v.y) + fabsf(v.z) + fabsf(v.w);
      }
    }
  }
  for (int off = 32; off; off >>= 1) s += __shfl_down(s, off);
  __shared__ double wsum[4];
  if (lane == 0) wsum[w] = (double)s;
  __syncthreads();
  if (threadIdx.x == 0) {
    ws->noise_partial[n][chunk] = (float)(wsum[0] + wsum[1] + wsum[2] + wsum[3]);
  }
}

// ---- K2: per-sample stats — VERBATIM from round-1 ---------------------------
__global__ __launch_bounds__(256) void k_stats(const float* __restrict__ x,
                                               WS* __restrict__ ws) {
  int n = blockIdx.x;
  int t = threadIdx.x;
  const float* p = x + (size_t)n * CFT + (size_t)FC_IDX * T_DIM + t;
  float m = fabsf(p[0]) + fabsf(p[FT]) + fabsf(p[2 * FT]);

  __shared__ float  smag[256];
  __shared__ float  sv[256];
  __shared__ int    si[256];
  __shared__ double sd[256];
  smag[t] = m; sv[t] = m; si[t] = t;
  sd[t] = (t < NCHUNK) ? (double)ws->noise_partial[n][t] : 0.0;
  __syncthreads();
  for (int s = 128; s > 0; s >>= 1) {
    if (t < s) {
      if (sv[t + s] > sv[t] || (sv[t + s] == sv[t] && si[t + s] < si[t])) {
        sv[t] = sv[t + s]; si[t] = si[t + s];
      }
      sd[t] += sd[t + s];
    }
    __syncthreads();
  }
  if (t == 0) {
    int mid = si[0];
    double noise_d = sd[0] / ((double)N_NOISE * (double)T_DIM);
    int lo = mid - 8; if (lo < 0) lo = 0;
    int hi = mid + 8; if (hi > T_DIM) hi = T_DIM;
    double sig_d = 0.0;
    for (int tt = lo; tt < hi; ++tt) sig_d += (double)smag[tt];
    float sig = (float)sig_d, noise = (float)noise_d;
    float d   = sig - noise;
    float snr = 10.0f * log10f((d * d) / (noise * noise));
    float hbf = 12.5f * (snr - 20.0f) + 27.0f;
    int hb = (int)truncf(hbf);
    if (hb < 8) hb = 8;
    ws->mid[n] = mid;
    ws->hb[n]  = hb;
    int wlo = mid - 8, whi = mid + 8;
    #pragma unroll
    for (int wd = 0; wd < 4; ++wd) {
      int base = wd * 64;
      int a = wlo - base; if (a < 0) a = 0;
      int b = whi - base; if (b > 64) b = 64;
      unsigned long long msk = 0ULL;
      if (b > a) {
        unsigned long long hiM = (b >= 64) ? ~0ULL : ((1ULL << b) - 1ULL);
        unsigned long long loM = (1ULL << a) - 1ULL;
        msk = hiM & ~loM;
      }
      ws->tbits[n][wd] = msk;
    }
  }
}

// ---- K3: division-free full-output write, one wave per freq row -------------
// grid (820, 4): wave w of block bx owns row f = bx*4+w; blockIdx.y selects a
// group of 24 planes. Union time-mask computed in registers per lane; x read
// only where mask bits are set (~4% of rows); everything else is a pure
// 1 KB-per-wave-instruction zero store stream.
__global__ __launch_bounds__(256) void k_out(const float4* __restrict__ xv,
                                             float4* __restrict__ ov,
                                             const WS* __restrict__ ws) {
  int w    = threadIdx.x >> 6;        // wave 0..3
  int lane = threadIdx.x & 63;        // lane = float4 index within the row
  int f    = blockIdx.x * 4 + w;
  if (f >= F_DIM) return;             // only block 819, waves 1..3

  // per-lane union mask word: lane covers times [4*lane, 4*lane+4)
  int word_idx = lane >> 4;           // which 64-bit tbits word
  unsigned long long m = 0ULL;
  #pragma unroll 4
  for (int n = 0; n < N_S; ++n) {
    int hb = ws->hb[n];
    if (f >= FC_IDX - hb && f < FC_IDX + hb) m |= ws->tbits[n][word_idx];
  }
  unsigned bits = (unsigned)(m >> ((lane & 15) * 4)) & 0xFu;

  const float4* xr  = xv + (size_t)f * 64 + lane;
  float4*       orw = ov + (size_t)f * 64 + lane;
  int p0 = blockIdx.y * (PLANES / 4);
  #pragma unroll 4
  for (int p = p0; p < p0 + PLANES / 4; ++p) {
    size_t off = (size_t)p * P4;
    float4 r = {0.f, 0.f, 0.f, 0.f};
    if (bits) {
      float4 v = xr[off];
      if (bits & 1u) r.x = v.x;
      if (bits & 2u) r.y = v.y;
      if (bits & 4u) r.z = v.z;
      if (bits & 8u) r.w = v.w;
    }
    orw[off] = r;
  }
}

extern "C" void kernel_launch(void* const* d_in, const int* in_sizes, int n_in,
                              void* d_out, int out_size, void* d_ws, size_t ws_size,
                              hipStream_t stream) {
  const float* x   = (const float*)d_in[0];
  float*       out = (float*)d_out;
  WS*          ws  = (WS*)d_ws;

  k_noise<<<N_S * NCHUNK, 256, 0, stream>>>(x, ws);
  k_stats<<<N_S, 256, 0, stream>>>(x, ws);
  dim3 g((F_DIM + 3) / 4, 4);
  k_out <<<g, 256, 0, stream>>>((const float4*)x, (float4*)out, ws);
}